// Round 7
// baseline (113.449 us; speedup 1.0000x reference)
//
#include <hip/hip_runtime.h>
#include <hip/hip_bf16.h>

#define B_ 4
#define L_ 1024
#define E_ 256
#define S_ 32

typedef __bf16 bf16x8 __attribute__((ext_vector_type(8)));
typedef float f32x4 __attribute__((ext_vector_type(4)));
typedef float f32x2 __attribute__((ext_vector_type(2)));

__device__ __forceinline__ __bf16 bf_from_bits(unsigned short u) {
    __bf16 b;
    __builtin_memcpy(&b, &u, 2);
    return b;
}

// Raw v_exp_f32 (2^x). libm exp2f lowers to the OCML denormal-correct wrapper
// (~5 VALU fixup/call); raw is safe here (denormal softmax terms ~ 0).
// Confirmed win round 4.
__device__ __forceinline__ float fexp2(float x) {
#if __has_builtin(__builtin_amdgcn_exp2f)
    return __builtin_amdgcn_exp2f(x);
#else
    return exp2f(x);
#endif
}

__device__ __forceinline__ f32x2 vexp2(f32x2 t) {
    f32x2 r;
    r.x = fexp2(t.x);
    r.y = fexp2(t.y);
    return r;
}

// Split fp32 -> bf16 hi (truncate) + bf16 lo (residual). a ~= hi + lo with
// ~2^-17 rel error when both terms are used in the MFMA product expansion.
__device__ __forceinline__ void load8split(const float* __restrict__ p,
                                           bf16x8& h, bf16x8& l) {
    const float4 x0 = *(const float4*)p;
    const float4 x1 = *(const float4*)(p + 4);
    const float xs[8] = {x0.x, x0.y, x0.z, x0.w, x1.x, x1.y, x1.z, x1.w};
#pragma unroll
    for (int j = 0; j < 8; ++j) {
        const unsigned hb = __float_as_uint(xs[j]) & 0xFFFF0000u;
        h[j] = bf_from_bits((unsigned short)(hb >> 16));
        l[j] = (__bf16)(xs[j] - __uint_as_float(hb));
    }
}

// ===========================================================================
// PATH A kernel 1: Q/K/V projections (unchanged, ~4-5 us, near its floor).
// ===========================================================================
__global__ __launch_bounds__(256, 1) void qkv_gemm2(
    const float* __restrict__ A,
    const float* __restrict__ Wq, const float* __restrict__ bq,
    const float* __restrict__ Wk, const float* __restrict__ bk,
    const float* __restrict__ Wv, const float* __restrict__ bv,
    float* __restrict__ Qo, float* __restrict__ Ko, float* __restrict__ Vo)
{
    const float* Wm;
    const float* bm;
    float* Om;
    const int z = blockIdx.z;
    if (z == 0)      { Wm = Wq; bm = bq; Om = Qo; }
    else if (z == 1) { Wm = Wk; bm = bk; Om = Ko; }
    else             { Wm = Wv; bm = bv; Om = Vo; }

    const int wave = threadIdx.x >> 6;
    const int lane = threadIdx.x & 63;
    const int rsel = lane & 15;
    const int koff = (lane >> 4) * 8;

    const int m0 = blockIdx.x * 32;
    const int nb = wave * 64;

    const float* pa0 = A + (size_t)(m0 + rsel) * 256 + koff;
    const float* pa1 = pa0 + (size_t)16 * 256;
    const float* pw0 = Wm + (size_t)(nb + 0  + rsel) * 256 + koff;
    const float* pw1 = Wm + (size_t)(nb + 16 + rsel) * 256 + koff;
    const float* pw2 = Wm + (size_t)(nb + 32 + rsel) * 256 + koff;
    const float* pw3 = Wm + (size_t)(nb + 48 + rsel) * 256 + koff;

    f32x4 acc[2][4];
#pragma unroll
    for (int mt = 0; mt < 2; ++mt)
#pragma unroll
        for (int nt = 0; nt < 4; ++nt)
            acc[mt][nt] = (f32x4){0.f, 0.f, 0.f, 0.f};

#pragma unroll
    for (int k0 = 0; k0 < 256; k0 += 32) {
        bf16x8 ah[2], al[2], bh[4], bl[4];
        load8split(pa0 + k0, ah[0], al[0]);
        load8split(pa1 + k0, ah[1], al[1]);
        load8split(pw0 + k0, bh[0], bl[0]);
        load8split(pw1 + k0, bh[1], bl[1]);
        load8split(pw2 + k0, bh[2], bl[2]);
        load8split(pw3 + k0, bh[3], bl[3]);
#pragma unroll
        for (int mt = 0; mt < 2; ++mt)
#pragma unroll
            for (int nt = 0; nt < 4; ++nt) {
                acc[mt][nt] = __builtin_amdgcn_mfma_f32_16x16x32_bf16(
                    ah[mt], bh[nt], acc[mt][nt], 0, 0, 0);
                acc[mt][nt] = __builtin_amdgcn_mfma_f32_16x16x32_bf16(
                    ah[mt], bl[nt], acc[mt][nt], 0, 0, 0);
                acc[mt][nt] = __builtin_amdgcn_mfma_f32_16x16x32_bf16(
                    al[mt], bh[nt], acc[mt][nt], 0, 0, 0);
            }
    }

#pragma unroll
    for (int mt = 0; mt < 2; ++mt) {
        const int mrow = m0 + mt * 16 + (lane >> 4) * 4;
#pragma unroll
        for (int nt = 0; nt < 4; ++nt) {
            const int n = nb + nt * 16 + rsel;
            const float bias = bm[n];
#pragma unroll
            for (int r = 0; r < 4; ++r)
                Om[(size_t)(mrow + r) * 256 + n] = acc[mt][nt][r] + bias;
        }
    }
}

// ===========================================================================
// PATH A kernel 2 (v9): windowed per-channel softmax + context + sigmoid^2.
// Structure = v8 (4-row pairing, 2ch/thread packed f32x2, 128-thr blocks).
// Single change: INTERIOR t-LOOP FULLY UNROLLED. Evidence: occupancy x2 (v6),
// DS/2 (v7), VALU/2 (v8) each moved <=1.6us -> stage-2 is not pipe-bound but
// latency-bound: the unroll-2 window + rolling-P rotation kept ds_reads only
// ~1 step ahead of use, and 2 waves/SIMD can't hide ~40-70cy lgkmcnt stalls.
// Full unroll makes all 60 interior steps straight-line SSA (t compile-time,
// h-rotation dissolves) so the scheduler hoists ds_reads to the VGPR cap
// (256 at launch_bounds(128,2); base live state ~40 VGPR).
// Edge blocks (2 of 32) stay unroll-2 to bound code size.
// ===========================================================================
#define TI7 32          // i-rows per block (8 quads)
#define CH7 32          // channels per block
#define HR7 96          // staged rows: j in [i0-S, i0+TI7-1+S]
#define PS7 36          // padded LDS stride (floats)

#define STEP4I(T, PNEW, PH1, PH2, PH3)                                   \
    {                                                                    \
        const int rl = rb + (T);                                         \
        const f32x2 kk = *(const f32x2*)&Kw[rl][c];                      \
        const f32x2 vv = *(const f32x2*)&Vw[rl][c];                      \
        PNEW = *(const f32x2*)&Pw[(T)][c];                               \
        const f32x2 e0 = vexp2(qs0 * (kk + PNEW));                       \
        const f32x2 e1 = vexp2(qs1 * (kk + PH1));                        \
        const f32x2 e2 = vexp2(qs2 * (kk + PH2));                        \
        const f32x2 e3 = vexp2(qs3 * (kk + PH3));                        \
        d0 += e0; n0 += e0 * vv;                                         \
        d1 += e1; n1 += e1 * vv;                                         \
        d2 += e2; n2 += e2 * vv;                                         \
        d3 += e3; n3 += e3 * vv;                                         \
    }

#define STEP4E(T, PNEW, PH1, PH2, PH3)                                   \
    {                                                                    \
        const int jj = iA - S_ + (T);                                    \
        const float m = (jj >= 0 && jj <= L_ - 1) ? 1.f : 0.f;           \
        const int rl = rb + (T);                                         \
        const f32x2 kk = *(const f32x2*)&Kw[rl][c];                      \
        const f32x2 vv = *(const f32x2*)&Vw[rl][c];                      \
        PNEW = *(const f32x2*)&Pw[(T)][c];                               \
        const f32x2 e0 = m * vexp2(qs0 * (kk + PNEW));                   \
        const f32x2 e1 = m * vexp2(qs1 * (kk + PH1));                    \
        const f32x2 e2 = m * vexp2(qs2 * (kk + PH2));                    \
        const f32x2 e3 = m * vexp2(qs3 * (kk + PH3));                    \
        d0 += e0; n0 += e0 * vv;                                         \
        d1 += e1; n1 += e1 * vv;                                         \
        d2 += e2; n2 += e2 * vv;                                         \
        d3 += e3; n3 += e3 * vv;                                         \
    }

__global__ __launch_bounds__(128, 2) void aft_stage2i(
    const float* __restrict__ Q, const float* __restrict__ K,
    const float* __restrict__ V, const float* __restrict__ pb,
    float* __restrict__ out)
{
    __shared__ float Kw[HR7][PS7];        // 13824 B
    __shared__ float Vw[HR7][PS7];        // 13824 B
    __shared__ float Pw[2 * S_ + 1][PS7]; //  9360 B (total 37008 B, 4 blk/CU)

    const int tid = threadIdx.x;          // 0..127
    const int b  = blockIdx.y;
    const int i0 = blockIdx.x * TI7;
    const int c0 = blockIdx.z * CH7;

    const int duo = tid & 15;             // channel duo 0..15
    const int qd  = tid >> 4;             // row quad 0..7
    const int c   = duo * 2;
    const int iA  = i0 + qd * 4;          // rows iA .. iA+3
    const int rb  = qd * 4;               // LDS row of j = iA - S at t=0

    // Q reads issued before staging; complete under the barrier.
    const float* Qr = Q + ((size_t)b * L_ + iA) * E_ + c0 + c;
    const f32x2 qv0 = *(const f32x2*)(Qr);
    const f32x2 qv1 = *(const f32x2*)(Qr + E_);
    const f32x2 qv2 = *(const f32x2*)(Qr + 2 * E_);
    const f32x2 qv3 = *(const f32x2*)(Qr + 3 * E_);

    const float* Kb = K + (size_t)b * L_ * E_;
    const float* Vb = V + (size_t)b * L_ * E_;

    // ---- stage K/V halo rows (96 rows x 32 ch), 128 threads ----
    for (int idx = tid; idx < HR7 * 8; idx += 128) {
        const int r = idx >> 3;
        const int cc = (idx & 7) * 4;
        int j = i0 - S_ + r;
        j = j < 0 ? 0 : (j > L_ - 1 ? L_ - 1 : j);   // clamped rows are masked
        const size_t g = (size_t)j * E_ + c0 + cc;
        *(float4*)&Kw[r][cc] = *(const float4*)(Kb + g);
        *(float4*)&Vw[r][cc] = *(const float4*)(Vb + g);
    }
    // ---- stage pos_bias slice (65 rows x 32 ch) ----
    for (int idx = tid; idx < (2 * S_ + 1) * 8; idx += 128) {
        const int r = idx >> 3;
        const int cc = (idx & 7) * 4;
        *(float4*)&Pw[r][cc] = *(const float4*)(pb + (size_t)r * E_ + c0 + cc);
    }
    __syncthreads();

    const float LOG2E = 1.44269504088896340736f;
    const f32x2 qs0 = qv0 * LOG2E;
    const f32x2 qs1 = qv1 * LOG2E;
    const f32x2 qs2 = qv2 * LOG2E;
    const f32x2 qs3 = qv3 * LOG2E;

    f32x2 d0 = {0.f, 0.f}, n0 = {0.f, 0.f};
    f32x2 d1 = {0.f, 0.f}, n1 = {0.f, 0.f};
    f32x2 d2 = {0.f, 0.f}, n2 = {0.f, 0.f};
    f32x2 d3 = {0.f, 0.f}, n3 = {0.f, 0.f};

    f32x2 p0, h1, h2, h3;

    const bool interior = (blockIdx.x >= 1) && (blockIdx.x <= (L_ / TI7) - 2);

    if (interior) {
        // ---- head t=0..3: w=0 peels (e=1) + early regular taps ----
        {   // t=0: row0 peel only
            const f32x2 vv = *(const f32x2*)&Vw[rb][c];
            d0 += 1.f; n0 += vv;
        }
        {   // t=1: row0 w=1; row1 peel
            const f32x2 kk = *(const f32x2*)&Kw[rb + 1][c];
            const f32x2 vv = *(const f32x2*)&Vw[rb + 1][c];
            h3 = *(const f32x2*)&Pw[1][c];               // P[1]
            const f32x2 e0 = vexp2(qs0 * (kk + h3));
            d0 += e0; n0 += e0 * vv;
            d1 += 1.f; n1 += vv;
        }
        {   // t=2: row0 w=2; row1 w=1; row2 peel
            const f32x2 kk = *(const f32x2*)&Kw[rb + 2][c];
            const f32x2 vv = *(const f32x2*)&Vw[rb + 2][c];
            h2 = *(const f32x2*)&Pw[2][c];               // P[2]
            const f32x2 e0 = vexp2(qs0 * (kk + h2));
            const f32x2 e1 = vexp2(qs1 * (kk + h3));
            d0 += e0; n0 += e0 * vv;
            d1 += e1; n1 += e1 * vv;
            d2 += 1.f; n2 += vv;
        }
        {   // t=3: row0 w=3; row1 w=2; row2 w=1; row3 peel
            const f32x2 kk = *(const f32x2*)&Kw[rb + 3][c];
            const f32x2 vv = *(const f32x2*)&Vw[rb + 3][c];
            h1 = *(const f32x2*)&Pw[3][c];               // P[3]
            const f32x2 e0 = vexp2(qs0 * (kk + h1));
            const f32x2 e1 = vexp2(qs1 * (kk + h2));
            const f32x2 e2 = vexp2(qs2 * (kk + h3));
            d0 += e0; n0 += e0 * vv;
            d1 += e1; n1 += e1 * vv;
            d2 += e2; n2 += e2 * vv;
            d3 += 1.f; n3 += vv;
        }
        // entry invariant: h1=P[t-1], h2=P[t-2], h3=P[t-3].
        // FULL unroll: straight-line SSA, ds_reads hoistable to VGPR cap.
#pragma unroll
        for (int t = 4; t <= 60; t += 4) {
            STEP4I(t + 0, p0, h1, h2, h3)
            STEP4I(t + 1, h3, p0, h1, h2)
            STEP4I(t + 2, h2, h3, p0, h1)
            STEP4I(t + 3, h1, h2, h3, p0)
        }
        // after loop: h1=P[63], h2=P[62], h3=P[61]
        // ---- tail t=64..67: w=64 peels (e=1) + late regular taps ----
        {   // t=64: row0 peel; row1 w=63(h1); row2 w=62(h2); row3 w=61(h3)
            const f32x2 kk = *(const f32x2*)&Kw[rb + 64][c];
            const f32x2 vv = *(const f32x2*)&Vw[rb + 64][c];
            const f32x2 e1 = vexp2(qs1 * (kk + h1));
            const f32x2 e2 = vexp2(qs2 * (kk + h2));
            const f32x2 e3 = vexp2(qs3 * (kk + h3));
            d0 += 1.f; n0 += vv;
            d1 += e1; n1 += e1 * vv;
            d2 += e2; n2 += e2 * vv;
            d3 += e3; n3 += e3 * vv;
        }
        {   // t=65: row1 peel; row2 w=63(h1); row3 w=62(h2)
            const f32x2 kk = *(const f32x2*)&Kw[rb + 65][c];
            const f32x2 vv = *(const f32x2*)&Vw[rb + 65][c];
            const f32x2 e2 = vexp2(qs2 * (kk + h1));
            const f32x2 e3 = vexp2(qs3 * (kk + h2));
            d1 += 1.f; n1 += vv;
            d2 += e2; n2 += e2 * vv;
            d3 += e3; n3 += e3 * vv;
        }
        {   // t=66: row2 peel; row3 w=63(h1)
            const f32x2 kk = *(const f32x2*)&Kw[rb + 66][c];
            const f32x2 vv = *(const f32x2*)&Vw[rb + 66][c];
            const f32x2 e3 = vexp2(qs3 * (kk + h1));
            d2 += 1.f; n2 += vv;
            d3 += e3; n3 += e3 * vv;
        }
        {   // t=67: row3 peel
            const f32x2 vv = *(const f32x2*)&Vw[rb + 67][c];
            d3 += 1.f; n3 += vv;
        }
    } else {
        // ---- edge blocks: every step masked by j-validity (shared by rows) ----
        {   // t=0: row0 peel
            const int jj = iA - S_;
            const float m = (jj >= 0) ? 1.f : 0.f;
            const f32x2 vv = *(const f32x2*)&Vw[rb][c];
            d0 += m; n0 += m * vv;
        }
        {   // t=1
            const int jj = iA - S_ + 1;
            const float m = (jj >= 0 && jj <= L_ - 1) ? 1.f : 0.f;
            const f32x2 kk = *(const f32x2*)&Kw[rb + 1][c];
            const f32x2 vv = *(const f32x2*)&Vw[rb + 1][c];
            h3 = *(const f32x2*)&Pw[1][c];
            const f32x2 e0 = m * vexp2(qs0 * (kk + h3));
            d0 += e0; n0 += e0 * vv;
            d1 += m;  n1 += m * vv;
        }
        {   // t=2
            const int jj = iA - S_ + 2;
            const float m = (jj >= 0 && jj <= L_ - 1) ? 1.f : 0.f;
            const f32x2 kk = *(const f32x2*)&Kw[rb + 2][c];
            const f32x2 vv = *(const f32x2*)&Vw[rb + 2][c];
            h2 = *(const f32x2*)&Pw[2][c];
            const f32x2 e0 = m * vexp2(qs0 * (kk + h2));
            const f32x2 e1 = m * vexp2(qs1 * (kk + h3));
            d0 += e0; n0 += e0 * vv;
            d1 += e1; n1 += e1 * vv;
            d2 += m;  n2 += m * vv;
        }
        {   // t=3
            const int jj = iA - S_ + 3;
            const float m = (jj >= 0 && jj <= L_ - 1) ? 1.f : 0.f;
            const f32x2 kk = *(const f32x2*)&Kw[rb + 3][c];
            const f32x2 vv = *(const f32x2*)&Vw[rb + 3][c];
            h1 = *(const f32x2*)&Pw[3][c];
            const f32x2 e0 = m * vexp2(qs0 * (kk + h1));
            const f32x2 e1 = m * vexp2(qs1 * (kk + h2));
            const f32x2 e2 = m * vexp2(qs2 * (kk + h3));
            d0 += e0; n0 += e0 * vv;
            d1 += e1; n1 += e1 * vv;
            d2 += e2; n2 += e2 * vv;
            d3 += m;  n3 += m * vv;
        }
#pragma unroll 2
        for (int t = 4; t <= 60; t += 4) {
            STEP4E(t + 0, p0, h1, h2, h3)
            STEP4E(t + 1, h3, p0, h1, h2)
            STEP4E(t + 2, h2, h3, p0, h1)
            STEP4E(t + 3, h1, h2, h3, p0)
        }
        {   // t=64
            const int jj = iA - S_ + 64;
            const float m = (jj >= 0 && jj <= L_ - 1) ? 1.f : 0.f;
            const f32x2 kk = *(const f32x2*)&Kw[rb + 64][c];
            const f32x2 vv = *(const f32x2*)&Vw[rb + 64][c];
            const f32x2 e1 = m * vexp2(qs1 * (kk + h1));
            const f32x2 e2 = m * vexp2(qs2 * (kk + h2));
            const f32x2 e3 = m * vexp2(qs3 * (kk + h3));
            d0 += m;  n0 += m * vv;
            d1 += e1; n1 += e1 * vv;
            d2 += e2; n2 += e2 * vv;
            d3 += e3; n3 += e3 * vv;
        }
        {   // t=65
            const int jj = iA - S_ + 65;
            const float m = (jj >= 0 && jj <= L_ - 1) ? 1.f : 0.f;
            const f32x2 kk = *(const f32x2*)&Kw[rb + 65][c];
            const f32x2 vv = *(const f32x2*)&Vw[rb + 65][c];
            const f32x2 e2 = m * vexp2(qs2 * (kk + h1));
            const f32x2 e3 = m * vexp2(qs3 * (kk + h2));
            d1 += m;  n1 += m * vv;
            d2 += e2; n2 += e2 * vv;
            d3 += e3; n3 += e3 * vv;
        }
        {   // t=66
            const int jj = iA - S_ + 66;
            const float m = (jj >= 0 && jj <= L_ - 1) ? 1.f : 0.f;
            const f32x2 kk = *(const f32x2*)&Kw[rb + 66][c];
            const f32x2 vv = *(const f32x2*)&Vw[rb + 66][c];
            const f32x2 e3 = m * vexp2(qs3 * (kk + h1));
            d2 += m;  n2 += m * vv;
            d3 += e3; n3 += e3 * vv;
        }
        {   // t=67
            const int jj = iA - S_ + 67;
            const float m = (jj >= 0 && jj <= L_ - 1) ? 1.f : 0.f;
            const f32x2 vv = *(const f32x2*)&Vw[rb + 67][c];
            d3 += m; n3 += m * vv;
        }
    }

    // sigmoid via raw exp2 (reuse qs = q*log2e): sig = 1/(1+2^-qs)
    f32x2 s0, s1, s2, s3;
    s0.x = 1.f / (1.f + fexp2(-qs0.x)); s0.y = 1.f / (1.f + fexp2(-qs0.y));
    s1.x = 1.f / (1.f + fexp2(-qs1.x)); s1.y = 1.f / (1.f + fexp2(-qs1.y));
    s2.x = 1.f / (1.f + fexp2(-qs2.x)); s2.y = 1.f / (1.f + fexp2(-qs2.y));
    s3.x = 1.f / (1.f + fexp2(-qs3.x)); s3.y = 1.f / (1.f + fexp2(-qs3.y));

    float* ob = out + ((size_t)b * L_ + iA) * E_ + c0 + c;
    *(f32x2*)(ob)          = s0 * s0 * n0 / d0;
    *(f32x2*)(ob + E_)     = s1 * s1 * n1 / d1;
    *(f32x2*)(ob + 2 * E_) = s2 * s2 * n2 / d2;
    *(f32x2*)(ob + 3 * E_) = s3 * s3 * n3 / d3;
}

// ===========================================================================
// PATH B (ws too small; fallback only): fully fused, fp32.
// ===========================================================================
#define TI 32
#define CG 64
#define RK 96
#define LDP 68

__global__ __launch_bounds__(256) void aft_fused(
    const float* __restrict__ q,
    const float* __restrict__ Wq, const float* __restrict__ bq,
    const float* __restrict__ Wk, const float* __restrict__ bk,
    const float* __restrict__ Wv, const float* __restrict__ bv,
    const float* __restrict__ pb,
    float* __restrict__ out)
{
    __shared__ float Kl[RK][LDP];
    __shared__ float Vl[RK][LDP];
    __shared__ float Ql[TI][LDP];

    const int i0 = blockIdx.x * TI;
    const int b  = blockIdx.y;
    const int c0 = blockIdx.z * CG;

    const int wave = threadIdx.x >> 6;
    const int lane = threadIdx.x & 63;
    const int rsel = lane & 15;
    const int koff = (lane >> 4) * 8;

    const float* qb = q + (size_t)b * L_ * E_;

    for (int job = wave; job < 56; job += 4) {
        int p, rt, ct;
        if (job < 24)      { p = 0; rt = job >> 2;        ct = job & 3; }
        else if (job < 48) { p = 1; rt = (job - 24) >> 2; ct = (job - 24) & 3; }
        else               { p = 2; rt = (job - 48) >> 2; ct = (job - 48) & 3; }

        int jrow = (p == 2) ? (i0 + rt * 16 + rsel)
                            : (i0 - S_ + rt * 16 + rsel);
        int jc = jrow < 0 ? 0 : (jrow > L_ - 1 ? L_ - 1 : jrow);
        const float* pa = qb + (size_t)jc * E_ + koff;

        const float* Wm = (p == 0) ? Wk : (p == 1) ? Wv : Wq;
        const float* bm = (p == 0) ? bk : (p == 1) ? bv : bq;
        const int n = c0 + ct * 16 + rsel;
        const float* pw = Wm + (size_t)n * E_ + koff;

        f32x4 acc = {0.f, 0.f, 0.f, 0.f};
#pragma unroll
        for (int k0 = 0; k0 < 256; k0 += 32) {
            bf16x8 ah, al, bh, bl;
            load8split(pa + k0, ah, al);
            load8split(pw + k0, bh, bl);
            acc = __builtin_amdgcn_mfma_f32_16x16x32_bf16(ah, bh, acc, 0, 0, 0);
            acc = __builtin_amdgcn_mfma_f32_16x16x32_bf16(ah, bl, acc, 0, 0, 0);
            acc = __builtin_amdgcn_mfma_f32_16x16x32_bf16(al, bh, acc, 0, 0, 0);
        }

        const float bias = bm[n];
        const int row0 = rt * 16 + (lane >> 4) * 4;
        const int colc = ct * 16 + rsel;
        float* dst = (p == 0) ? &Kl[0][0] : (p == 1) ? &Vl[0][0] : &Ql[0][0];
#pragma unroll
        for (int r = 0; r < 4; ++r)
            dst[(size_t)(row0 + r) * LDP + colc] = acc[r] + bias;
    }
    __syncthreads();

    const int cq  = threadIdx.x & 15;
    const int is0 = threadIdx.x >> 4;
    const int cL  = cq * 4;
    const int cG  = c0 + cL;
    const float* pbc = pb + cG;

    for (int rr = is0; rr < TI; rr += 16) {
        const int i = i0 + rr;
        const float4 qv = *(const float4*)&Ql[rr][cL];

        float den0 = 0.f, den1 = 0.f, den2 = 0.f, den3 = 0.f;
        float num0 = 0.f, num1 = 0.f, num2 = 0.f, num3 = 0.f;

        const int jlo = (i - S_ < 0) ? 0 : (i - S_);
        const int jhi = (i + S_ > L_ - 1) ? (L_ - 1) : (i + S_);

        for (int j = jlo; j <= jhi; ++j) {
            const int r = j - (i0 - S_);
            const int w = j - i + S_;
            const float4 vv = *(const float4*)&Vl[r][cL];

            float kx = 0.f, ky = 0.f, kz = 0.f, kw = 0.f;
            if (w != 0 && w != 2 * S_) {
                const float4 kk = *(const float4*)&Kl[r][cL];
                const float4 pp = *(const float4*)(pbc + (size_t)w * E_);
                kx = kk.x + pp.x;
                ky = kk.y + pp.y;
                kz = kk.z + pp.z;
                kw = kk.w + pp.w;
            }
            const float e0 = __expf(qv.x * kx);
            const float e1 = __expf(qv.y * ky);
            const float e2 = __expf(qv.z * kz);
            const float e3 = __expf(qv.w * kw);
            den0 += e0; den1 += e1; den2 += e2; den3 += e3;
            num0 += e0 * vv.x; num1 += e1 * vv.y;
            num2 += e2 * vv.z; num3 += e3 * vv.w;
        }

        const float s0 = 1.f / (1.f + __expf(-qv.x));
        const float s1 = 1.f / (1.f + __expf(-qv.y));
        const float s2 = 1.f / (1.f + __expf(-qv.z));
        const float s3 = 1.f / (1.f + __expf(-qv.w));

        float4 o;
        o.x = s0 * s0 * num0 / den0;
        o.y = s1 * s1 * num1 / den1;
        o.z = s2 * s2 * num2 / den2;
        o.w = s3 * s3 * num3 / den3;
        *(float4*)(out + ((size_t)b * L_ + i) * E_ + cG) = o;
    }
}

extern "C" void kernel_launch(void* const* d_in, const int* in_sizes, int n_in,
                              void* d_out, int out_size, void* d_ws, size_t ws_size,
                              hipStream_t stream) {
    const float* q  = (const float*)d_in[0];
    const float* Wq = (const float*)d_in[1];
    const float* bq = (const float*)d_in[2];
    const float* Wk = (const float*)d_in[3];
    const float* bk = (const float*)d_in[4];
    const float* Wv = (const float*)d_in[5];
    const float* bv = (const float*)d_in[6];
    const float* pb = (const float*)d_in[7];

    const size_t needA = (size_t)3 * 4096 * 256 * sizeof(float);  // 12.6 MB

    if (ws_size >= needA) {
        float* Qf = (float*)d_ws;
        float* Kf = Qf + (size_t)4096 * 256;
        float* Vf = Kf + (size_t)4096 * 256;
        qkv_gemm2<<<dim3(128, 1, 3), 256, 0, stream>>>(q, Wq, bq, Wk, bk, Wv, bv,
                                                       Qf, Kf, Vf);
        aft_stage2i<<<dim3(L_ / TI7, B_, E_ / CH7), 128, 0, stream>>>(
            Qf, Kf, Vf, pb, (float*)d_out);
    } else {
        aft_fused<<<dim3(L_ / TI, B_, E_ / CG), 256, 0, stream>>>(
            q, Wq, bq, Wk, bk, Wv, bv, pb, (float*)d_out);
    }
}